// Round 1
// baseline (61860.901 us; speedup 1.0000x reference)
//
#include <hip/hip_runtime.h>
#include <hip/hip_fp16.h>

#define T_LEN 65536
#define FDIM  128
#define NGATE 512   // 4*F for layer-2 LSTM

// ---------- fast math helpers ----------
__device__ __forceinline__ float frcp(float x) { return __builtin_amdgcn_rcpf(x); }
__device__ __forceinline__ float sigmoid_f(float x) { return frcp(1.f + __expf(-x)); }
__device__ __forceinline__ float tanh_f(float x) { return 1.f - 2.f * frcp(__expf(2.f * x) + 1.f); }

// ---------- DPP cross-lane reduce ----------
template<int CTRL, int ROWM, int BANKM, bool BC>
__device__ __forceinline__ float dpp_mov0(float x) {
  return __int_as_float(
      __builtin_amdgcn_update_dpp(0, __float_as_int(x), CTRL, ROWM, BANKM, BC));
}

// sum within aligned 8-lane groups; full sum valid in lanes with (lane&7) in [4,7]
__device__ __forceinline__ float red8(float a) {
  a += dpp_mov0<0xB1, 0xF, 0xF, true>(a);   // quad_perm(1,0,3,2): xor-1
  a += dpp_mov0<0x4E, 0xF, 0xF, true>(a);   // quad_perm(2,3,0,1): xor-2
  a += dpp_mov0<0x114, 0xF, 0xA, true>(a);  // row_shr:4, banks 1&3 only (no cross-8 leak)
  return a;
}

// sum within aligned 16-lane rows; full sum in lane 15 of each row
__device__ __forceinline__ float red16(float a) {
  a += dpp_mov0<0x111, 0xF, 0xF, true>(a);  // row_shr:1
  a += dpp_mov0<0x112, 0xF, 0xF, true>(a);  // row_shr:2
  a += dpp_mov0<0x114, 0xF, 0xF, true>(a);  // row_shr:4
  a += dpp_mov0<0x118, 0xF, 0xF, true>(a);  // row_shr:8
  return a;
}

union H8 { uint4 u; __half h[8]; };

// ---------------------------------------------------------------------------
// Phase A: gx2[t][p][j] = x[t,:] . W_ih2[row,:] + (b_ih2+b_hh2)[row]   (f16)
//   p = unit-pair (0..63), j = [i0,i1,f0,f1,g0,g1,o0,o1], row = (j>>1)*128 + 2p + (j&1)
// Thread (wave w, pl=lane>>3, q=lane&7): pair p = 8w+pl, k-range [16q,16q+16).
// ---------------------------------------------------------------------------
__global__ __launch_bounds__(512, 2)
void gx_kernel(const float* __restrict__ x, const float* __restrict__ Wih2,
               const float* __restrict__ bih2, const float* __restrict__ bhh2,
               __half* __restrict__ gx)
{
  __shared__ float xs[64 * FDIM];           // 32 KB tile of x
  const int tid  = threadIdx.x;
  const int lane = tid & 63;
  const int wave = tid >> 6;
  const int q    = lane & 7;
  const int pl   = lane >> 3;
  const int p    = wave * 8 + pl;
  const int u0   = 2 * p;

  float w[8][16];
  float bias[8];
#pragma unroll
  for (int j = 0; j < 8; ++j) {
    const int row = ((j >> 1) * 128) + u0 + (j & 1);
    const int base = row * FDIM + q * 16;
#pragma unroll
    for (int k = 0; k < 16; ++k) w[j][k] = Wih2[base + k];
    bias[j] = bih2[row] + bhh2[row];
  }

  const int t0 = blockIdx.x * 64;
  const float4* xg = (const float4*)(x + (size_t)t0 * FDIM);
  float4* xs4 = (float4*)xs;
#pragma unroll
  for (int i = 0; i < 4; ++i) xs4[tid + i * 512] = xg[tid + i * 512];
  __syncthreads();

  for (int tt = 0; tt < 64; ++tt) {
    float hv[16];
    const float4* hv4 = (const float4*)(xs + tt * FDIM + q * 16);
    *(float4*)&hv[0]  = hv4[0];
    *(float4*)&hv[4]  = hv4[1];
    *(float4*)&hv[8]  = hv4[2];
    *(float4*)&hv[12] = hv4[3];

    float acc[8];
#pragma unroll
    for (int j = 0; j < 8; ++j) {
      float a = 0.f;
#pragma unroll
      for (int k = 0; k < 16; ++k) a = fmaf(w[j][k], hv[k], a);
      acc[j] = red8(a);
    }
    if (q == 4) {
      H8 pk;
#pragma unroll
      for (int j = 0; j < 8; ++j) pk.h[j] = __float2half(acc[j] + bias[j]);
      *((uint4*)(gx + (size_t)(t0 + tt) * NGATE + p * 8)) = pk.u;
    }
  }
}

// ---------------------------------------------------------------------------
// Phase B: the sequential LSTM-2 scan.  One block, 512 threads, 8 waves.
// W_hh2 lives in registers (8 rows x 16 cols per thread = 128 VGPRs).
// h double-buffered in LDS (2x128 f32); gx2 prefetched 4 steps ahead.
// h2 history written to `hist` (= d_out), FC applied later in place.
// ---------------------------------------------------------------------------
__global__ __launch_bounds__(512, 2)
void scan_kernel(const __half* __restrict__ gx, const float* __restrict__ Whh2,
                 const float* __restrict__ h20, const float* __restrict__ c20,
                 float* __restrict__ hist)
{
  __shared__ __align__(16) float hb[2][FDIM];
  const int tid  = threadIdx.x;
  const int lane = tid & 63;
  const int wave = tid >> 6;
  const int q    = lane & 7;
  const int pl   = lane >> 3;
  const int p    = wave * 8 + pl;
  const int u0   = 2 * p;

  float w[8][16];
#pragma unroll
  for (int j = 0; j < 8; ++j) {
    const int row = ((j >> 1) * 128) + u0 + (j & 1);
#pragma unroll
    for (int k = 0; k < 16; ++k) w[j][k] = Whh2[row * FDIM + q * 16 + k];
  }

  float c0 = 0.f, c1 = 0.f;
  if (q == 4) { c0 = c20[u0]; c1 = c20[u0 + 1]; }
  if (tid < FDIM) hb[0][tid] = h20[tid];

  const bool loader = (q == 0);
  const uint4* gxv = (const uint4*)gx;      // 64 uint4 (8 halves each) per timestep
  uint4 gpf[4];
#pragma unroll
  for (int s = 0; s < 4; ++s) gpf[s] = gxv[s * 64 + p];

  __syncthreads();

  for (int t = 0; t < T_LEN; t += 4) {
#pragma unroll
    for (int s = 0; s < 4; ++s) {
      const int tt = t + s;
      // h_{t-1} from LDS (broadcast)
      float hv[16];
      const float4* hv4 = (const float4*)(&hb[tt & 1][q * 16]);
      *(float4*)&hv[0]  = hv4[0];
      *(float4*)&hv[4]  = hv4[1];
      *(float4*)&hv[8]  = hv4[2];
      *(float4*)&hv[12] = hv4[3];

      // init accumulators with gx (only the q==0 lane contributes it once)
      H8 g8; g8.u = gpf[s];
      float acc[8];
#pragma unroll
      for (int j = 0; j < 8; ++j) acc[j] = loader ? __half2float(g8.h[j]) : 0.f;

      // refill this prefetch slot for step tt+4 (wraps harmlessly at the end)
      const int tn = (tt + 4) & (T_LEN - 1);
      gpf[s] = gxv[tn * 64 + p];

      // 128 FMAs: 8 gates x 16 k
#pragma unroll
      for (int j = 0; j < 8; ++j) {
        float a = acc[j];
#pragma unroll
        for (int k = 0; k < 16; ++k) a = fmaf(w[j][k], hv[k], a);
        acc[j] = red8(a);
      }

      if (q == 4) {   // reducer lane: full gate sums for units u0,u1
        c0 = sigmoid_f(acc[2]) * c0 + sigmoid_f(acc[0]) * tanh_f(acc[4]);
        c1 = sigmoid_f(acc[3]) * c1 + sigmoid_f(acc[1]) * tanh_f(acc[5]);
        const float h0 = sigmoid_f(acc[6]) * tanh_f(c0);
        const float h1 = sigmoid_f(acc[7]) * tanh_f(c1);
        *(float2*)&hb[(tt + 1) & 1][u0] = make_float2(h0, h1);
        *(float2*)(hist + (size_t)tt * FDIM + u0) = make_float2(h0, h1);
      }
      __syncthreads();
    }
  }
}

// ---------------------------------------------------------------------------
// Phase C: out[t] = 2*sigmoid(W_fc @ h2[t] + b_fc), in place on d_out.
// Thread (g = row-group of 4, q = lane&15): rows [4g,4g+4), k in [8q,8q+8).
// ---------------------------------------------------------------------------
__global__ __launch_bounds__(512, 2)
void fc_kernel(const float* __restrict__ Wfc, const float* __restrict__ bfc,
               float* __restrict__ io)
{
  __shared__ float hs[64 * FDIM];
  const int tid  = threadIdx.x;
  const int lane = tid & 63;
  const int wave = tid >> 6;
  const int q    = lane & 15;
  const int gl   = lane >> 4;
  const int g    = wave * 4 + gl;           // 0..31

  float w[4][8];
#pragma unroll
  for (int r = 0; r < 4; ++r)
#pragma unroll
    for (int k = 0; k < 8; ++k)
      w[r][k] = Wfc[(4 * g + r) * FDIM + q * 8 + k];
  const float4 bias = ((const float4*)bfc)[g];

  const int t0 = blockIdx.x * 64;
  float4* iog = (float4*)(io + (size_t)t0 * FDIM);
  float4* hs4 = (float4*)hs;
#pragma unroll
  for (int i = 0; i < 4; ++i) hs4[tid + i * 512] = iog[tid + i * 512];
  __syncthreads();          // all reads of this block's rows done before writes

  for (int tt = 0; tt < 64; ++tt) {
    float hv[8];
    const float4* hv4 = (const float4*)(hs + tt * FDIM + q * 8);
    *(float4*)&hv[0] = hv4[0];
    *(float4*)&hv[4] = hv4[1];
    float acc[4];
#pragma unroll
    for (int r = 0; r < 4; ++r) {
      float a = 0.f;
#pragma unroll
      for (int k = 0; k < 8; ++k) a = fmaf(w[r][k], hv[k], a);
      acc[r] = red16(a);
    }
    if (q == 15) {
      float4 o;
      o.x = 2.f * sigmoid_f(acc[0] + bias.x);
      o.y = 2.f * sigmoid_f(acc[1] + bias.y);
      o.z = 2.f * sigmoid_f(acc[2] + bias.z);
      o.w = 2.f * sigmoid_f(acc[3] + bias.w);
      *(float4*)(io + (size_t)(t0 + tt) * FDIM + 4 * g) = o;
    }
  }
}

// ---------------------------------------------------------------------------
extern "C" void kernel_launch(void* const* d_in, const int* in_sizes, int n_in,
                              void* d_out, int out_size, void* d_ws, size_t ws_size,
                              hipStream_t stream) {
  const float* x    = (const float*)d_in[0];
  // d_in[1..2]: h1_0/c1_0  -- layer-1 LSTM never affects the output: skipped.
  const float* h20  = (const float*)d_in[3];
  const float* c20  = (const float*)d_in[4];
  // d_in[5..8]: W_ih1/W_hh1/b_ih1/b_hh1 -- dead.
  const float* Wih2 = (const float*)d_in[9];
  const float* Whh2 = (const float*)d_in[10];
  const float* bih2 = (const float*)d_in[11];
  const float* bhh2 = (const float*)d_in[12];
  const float* Wfc  = (const float*)d_in[13];
  const float* bfc  = (const float*)d_in[14];

  float*  out = (float*)d_out;              // [T,128]: h2 history, then final out
  __half* gx  = (__half*)d_ws;              // [T,512] f16 precomputed gates (67 MB)

  gx_kernel<<<T_LEN / 64, 512, 0, stream>>>(x, Wih2, bih2, bhh2, gx);
  scan_kernel<<<1, 512, 0, stream>>>(gx, Whh2, h20, c20, out);
  fc_kernel<<<T_LEN / 64, 512, 0, stream>>>(Wfc, bfc, out);
}

// Round 2
// 52889.636 us; speedup vs baseline: 1.1696x; 1.1696x over previous
//
#include <hip/hip_runtime.h>
#include <hip/hip_fp16.h>

#define T_LEN 65536
#define FDIM  128
#define NGATE 512   // 4*F for layer-2 LSTM

typedef _Float16 h2_t __attribute__((ext_vector_type(2)));

// ---------- fast math helpers ----------
__device__ __forceinline__ float frcp(float x) { return __builtin_amdgcn_rcpf(x); }
#define LOG2E 1.4426950408889634f
__device__ __forceinline__ float sigmoid_f(float x) {
  return frcp(1.f + __builtin_amdgcn_exp2f(-LOG2E * x));
}
__device__ __forceinline__ float tanh_f(float x) {
  return 1.f - 2.f * frcp(__builtin_amdgcn_exp2f(2.f * LOG2E * x) + 1.f);
}

// ---------- DPP cross-lane reduce ----------
template<int CTRL, int ROWM, int BANKM, bool BC>
__device__ __forceinline__ float dpp_mov0(float x) {
  return __int_as_float(
      __builtin_amdgcn_update_dpp(0, __float_as_int(x), CTRL, ROWM, BANKM, BC));
}

// sum within aligned 8-lane groups; full sum valid in lanes with (lane&7) in [4,7]
__device__ __forceinline__ float red8(float a) {
  a += dpp_mov0<0xB1, 0xF, 0xF, true>(a);   // quad_perm(1,0,3,2): xor-1
  a += dpp_mov0<0x4E, 0xF, 0xF, true>(a);   // quad_perm(2,3,0,1): xor-2
  a += dpp_mov0<0x114, 0xF, 0xA, true>(a);  // row_shr:4, banks 1&3 only
  return a;
}

// sum within aligned 16-lane rows; full sum in lane 15 of each row
__device__ __forceinline__ float red16(float a) {
  a += dpp_mov0<0x111, 0xF, 0xF, true>(a);  // row_shr:1
  a += dpp_mov0<0x112, 0xF, 0xF, true>(a);  // row_shr:2
  a += dpp_mov0<0x114, 0xF, 0xF, true>(a);  // row_shr:4
  a += dpp_mov0<0x118, 0xF, 0xF, true>(a);  // row_shr:8
  return a;
}

union H8  { uint4 u; __half h[8]; };
union HV4 { uint4 u; h2_t v[4]; };

// barrier with ONLY the LDS drain: no vmcnt(0) round-trip per step.
// Safe because: h hand-off is LDS (lgkm); gx prefetch loads are consumed via
// compiler-inserted vmcnt data-dependency waits; hist stores are never read back.
#define LDS_BARRIER() asm volatile("s_waitcnt lgkmcnt(0)\n\ts_barrier" ::: "memory")

// ---------------------------------------------------------------------------
// Phase A: gx2[t][p][j] = x[t,:] . W_ih2[row,:] + (b_ih2+b_hh2)[row]   (f16)
//   p = unit-pair (0..63), j = [i0,i1,f0,f1,g0,g1,o0,o1], row = (j>>1)*128 + 2p + (j&1)
// ---------------------------------------------------------------------------
__global__ __launch_bounds__(512, 2)
void gx_kernel(const float* __restrict__ x, const float* __restrict__ Wih2,
               const float* __restrict__ bih2, const float* __restrict__ bhh2,
               __half* __restrict__ gx)
{
  __shared__ float xs[64 * FDIM];           // 32 KB tile of x
  const int tid  = threadIdx.x;
  const int lane = tid & 63;
  const int wave = tid >> 6;
  const int q    = lane & 7;
  const int pl   = lane >> 3;
  const int p    = wave * 8 + pl;
  const int u0   = 2 * p;

  float w[8][16];
  float bias[8];
#pragma unroll
  for (int j = 0; j < 8; ++j) {
    const int row = ((j >> 1) * 128) + u0 + (j & 1);
    const int base = row * FDIM + q * 16;
#pragma unroll
    for (int k = 0; k < 16; ++k) w[j][k] = Wih2[base + k];
    bias[j] = bih2[row] + bhh2[row];
  }

  const int t0 = blockIdx.x * 64;
  const float4* xg = (const float4*)(x + (size_t)t0 * FDIM);
  float4* xs4 = (float4*)xs;
#pragma unroll
  for (int i = 0; i < 4; ++i) xs4[tid + i * 512] = xg[tid + i * 512];
  __syncthreads();

  for (int tt = 0; tt < 64; ++tt) {
    float hv[16];
    const float4* hv4 = (const float4*)(xs + tt * FDIM + q * 16);
    *(float4*)&hv[0]  = hv4[0];
    *(float4*)&hv[4]  = hv4[1];
    *(float4*)&hv[8]  = hv4[2];
    *(float4*)&hv[12] = hv4[3];

    float acc[8];
#pragma unroll
    for (int j = 0; j < 8; ++j) {
      float a = 0.f;
#pragma unroll
      for (int k = 0; k < 16; ++k) a = fmaf(w[j][k], hv[k], a);
      acc[j] = red8(a);
    }
    if (q == 4) {
      H8 pk;
#pragma unroll
      for (int j = 0; j < 8; ++j) pk.h[j] = __float2half(acc[j] + bias[j]);
      *((uint4*)(gx + (size_t)(t0 + tt) * NGATE + p * 8)) = pk.u;
    }
  }
}

// ---------------------------------------------------------------------------
// Phase B: sequential LSTM-2 scan. One block, 512 threads, 8 waves.
// W_hh2 in registers as packed half2 (8 rows x 8 half2 = 64 VGPRs/thread).
// h double-buffered in LDS as f16 (2x128 halves = 512 B, max 2-way bank alias).
// Dot products via v_dot2_f32_f16 (fp32 accumulate). gx prefetched 4 deep.
// Per-step barrier drains lgkm ONLY (no vmcnt round-trip).
// Gate nonlinearities split across lanes q=4 (unit u0) and q=5 (unit u0+1).
// ---------------------------------------------------------------------------
__global__ __launch_bounds__(512, 2)
void scan_kernel(const __half* __restrict__ gx, const float* __restrict__ Whh2,
                 const float* __restrict__ h20, const float* __restrict__ c20,
                 float* __restrict__ hist)
{
  __shared__ __align__(16) __half hb[2][FDIM];
  const int tid  = threadIdx.x;
  const int lane = tid & 63;
  const int wave = tid >> 6;
  const int q    = lane & 7;
  const int pl   = lane >> 3;
  const int p    = wave * 8 + pl;
  const int u0   = 2 * p;

  // pack W_hh2 rows into half2: w2[j][m] covers k = q*16 + 2m, 2m+1
  h2_t w2[8][8];
#pragma unroll
  for (int j = 0; j < 8; ++j) {
    const int row = ((j >> 1) * 128) + u0 + (j & 1);
    const float* wr = Whh2 + row * FDIM + q * 16;
#pragma unroll
    for (int m = 0; m < 8; ++m) {
      h2_t t;
      t[0] = (_Float16)wr[2 * m];
      t[1] = (_Float16)wr[2 * m + 1];
      w2[j][m] = t;
    }
  }

  const bool gater = (q == 4) | (q == 5);
  const int  par   = q & 1;                 // q=4 -> unit u0, q=5 -> unit u0+1
  float c = 0.f;
  if (gater) c = c20[u0 + par];
  if (tid < FDIM) hb[0][tid] = __float2half(h20[tid]);

  const uint4* gxv = (const uint4*)gx;      // 64 uint4 (8 halves) per timestep
  uint4 gpf[4];
#pragma unroll
  for (int s = 0; s < 4; ++s) gpf[s] = gxv[s * 64 + p];

  LDS_BARRIER();

  for (int t = 0; t < T_LEN; t += 4) {
#pragma unroll
    for (int s = 0; s < 4; ++s) {
      const int tt = t + s;
      // h_{t-1} from LDS: 16 halves (32 B) per lane
      const __half* hbuf = hb[tt & 1] + q * 16;
      HV4 ha, hc;
      ha.u = *(const uint4*)(hbuf);
      hc.u = *(const uint4*)(hbuf + 8);

      const uint4 gcur = gpf[s];
      // refill this prefetch slot for step tt+4 (wraps harmlessly at the end)
      gpf[s] = gxv[((tt + 4) & (T_LEN - 1)) * 64 + p];

      float acc[8];
#pragma unroll
      for (int j = 0; j < 8; ++j) {
        float a = 0.f;
#pragma unroll
        for (int m = 0; m < 4; ++m)
          a = __builtin_amdgcn_fdot2(w2[j][m], ha.v[m], a, false);
#pragma unroll
        for (int m = 0; m < 4; ++m)
          a = __builtin_amdgcn_fdot2(w2[j][4 + m], hc.v[m], a, false);
        acc[j] = red8(a);
      }

      if (gater) {    // full gate sums live in lanes q in {4..7}; use 4,5
        H8 g8; g8.u = gcur;
        const float gi = (par ? acc[1] : acc[0]) + __half2float(g8.h[0 + par]);
        const float gf = (par ? acc[3] : acc[2]) + __half2float(g8.h[2 + par]);
        const float gg = (par ? acc[5] : acc[4]) + __half2float(g8.h[4 + par]);
        const float go = (par ? acc[7] : acc[6]) + __half2float(g8.h[6 + par]);
        c = sigmoid_f(gf) * c + sigmoid_f(gi) * tanh_f(gg);
        const float h = sigmoid_f(go) * tanh_f(c);
        hb[(tt + 1) & 1][u0 + par] = __float2half(h);
        hist[(size_t)tt * FDIM + u0 + par] = h;   // fire-and-forget
      }
      LDS_BARRIER();
    }
  }
}

// ---------------------------------------------------------------------------
// Phase C: out[t] = 2*sigmoid(W_fc @ h2[t] + b_fc), in place on d_out.
// ---------------------------------------------------------------------------
__global__ __launch_bounds__(512, 2)
void fc_kernel(const float* __restrict__ Wfc, const float* __restrict__ bfc,
               float* __restrict__ io)
{
  __shared__ float hs[64 * FDIM];
  const int tid  = threadIdx.x;
  const int lane = tid & 63;
  const int wave = tid >> 6;
  const int q    = lane & 15;
  const int gl   = lane >> 4;
  const int g    = wave * 4 + gl;           // 0..31

  float w[4][8];
#pragma unroll
  for (int r = 0; r < 4; ++r)
#pragma unroll
    for (int k = 0; k < 8; ++k)
      w[r][k] = Wfc[(4 * g + r) * FDIM + q * 8 + k];
  const float4 bias = ((const float4*)bfc)[g];

  const int t0 = blockIdx.x * 64;
  float4* iog = (float4*)(io + (size_t)t0 * FDIM);
  float4* hs4 = (float4*)hs;
#pragma unroll
  for (int i = 0; i < 4; ++i) hs4[tid + i * 512] = iog[tid + i * 512];
  __syncthreads();          // all reads of this block's rows done before writes

  for (int tt = 0; tt < 64; ++tt) {
    float hv[8];
    const float4* hv4 = (const float4*)(hs + tt * FDIM + q * 8);
    *(float4*)&hv[0] = hv4[0];
    *(float4*)&hv[4] = hv4[1];
    float acc[4];
#pragma unroll
    for (int r = 0; r < 4; ++r) {
      float a = 0.f;
#pragma unroll
      for (int k = 0; k < 8; ++k) a = fmaf(w[r][k], hv[k], a);
      acc[r] = red16(a);
    }
    if (q == 15) {
      float4 o;
      o.x = 2.f * sigmoid_f(acc[0] + bias.x);
      o.y = 2.f * sigmoid_f(acc[1] + bias.y);
      o.z = 2.f * sigmoid_f(acc[2] + bias.z);
      o.w = 2.f * sigmoid_f(acc[3] + bias.w);
      *(float4*)(io + (size_t)(t0 + tt) * FDIM + 4 * g) = o;
    }
  }
}

// ---------------------------------------------------------------------------
extern "C" void kernel_launch(void* const* d_in, const int* in_sizes, int n_in,
                              void* d_out, int out_size, void* d_ws, size_t ws_size,
                              hipStream_t stream) {
  const float* x    = (const float*)d_in[0];
  // d_in[1..2]: h1_0/c1_0  -- layer-1 LSTM never affects the output: skipped.
  const float* h20  = (const float*)d_in[3];
  const float* c20  = (const float*)d_in[4];
  // d_in[5..8]: W_ih1/W_hh1/b_ih1/b_hh1 -- dead.
  const float* Wih2 = (const float*)d_in[9];
  const float* Whh2 = (const float*)d_in[10];
  const float* bih2 = (const float*)d_in[11];
  const float* bhh2 = (const float*)d_in[12];
  const float* Wfc  = (const float*)d_in[13];
  const float* bfc  = (const float*)d_in[14];

  float*  out = (float*)d_out;              // [T,128]: h2 history, then final out
  __half* gx  = (__half*)d_ws;              // [T,512] f16 precomputed gates (67 MB)

  gx_kernel<<<T_LEN / 64, 512, 0, stream>>>(x, Wih2, bih2, bhh2, gx);
  scan_kernel<<<1, 512, 0, stream>>>(gx, Whh2, h20, c20, out);
  fc_kernel<<<T_LEN / 64, 512, 0, stream>>>(Wfc, bfc, out);
}

// Round 3
// 28349.686 us; speedup vs baseline: 2.1821x; 1.8656x over previous
//
#include <hip/hip_runtime.h>
#include <hip/hip_fp16.h>

#define T_LEN 65536
#define FDIM  128
#define NGATE 512   // 4*F for layer-2 LSTM

typedef _Float16 f16x8 __attribute__((ext_vector_type(8)));
typedef float    f32x4 __attribute__((ext_vector_type(4)));

// ---------- fast math helpers ----------
__device__ __forceinline__ float frcp(float x) { return __builtin_amdgcn_rcpf(x); }
#define LOG2E 1.4426950408889634f
__device__ __forceinline__ float sigmoid_f(float x) {
  return frcp(1.f + __builtin_amdgcn_exp2f(-LOG2E * x));
}
__device__ __forceinline__ float tanh_f(float x) {
  return 1.f - 2.f * frcp(__builtin_amdgcn_exp2f(2.f * LOG2E * x) + 1.f);
}

// ---------- DPP cross-lane reduce (Phase A/C only) ----------
template<int CTRL, int ROWM, int BANKM, bool BC>
__device__ __forceinline__ float dpp_mov0(float x) {
  return __int_as_float(
      __builtin_amdgcn_update_dpp(0, __float_as_int(x), CTRL, ROWM, BANKM, BC));
}
__device__ __forceinline__ float red8(float a) {
  a += dpp_mov0<0xB1, 0xF, 0xF, true>(a);   // quad_perm xor-1
  a += dpp_mov0<0x4E, 0xF, 0xF, true>(a);   // quad_perm xor-2
  a += dpp_mov0<0x114, 0xF, 0xA, true>(a);  // row_shr:4, banks 1&3
  return a;
}
__device__ __forceinline__ float red16(float a) {
  a += dpp_mov0<0x111, 0xF, 0xF, true>(a);
  a += dpp_mov0<0x112, 0xF, 0xF, true>(a);
  a += dpp_mov0<0x114, 0xF, 0xF, true>(a);
  a += dpp_mov0<0x118, 0xF, 0xF, true>(a);
  return a;
}

union H8 { uint4 u; __half h[8]; };
union G4 { uint2 u; __half h[4]; };

// barrier draining ONLY lgkm (LDS): no per-step vmcnt round-trip.
#define LDS_BARRIER() asm volatile("s_waitcnt lgkmcnt(0)\n\ts_barrier" ::: "memory")

// ---------------------------------------------------------------------------
// Phase A: per-unit gate precompute, stored as [T][128] x {i,f,g,o} f16 quads.
//   gx[t][u] = { x_t . W_ih2[u], x_t . W_ih2[128+u], ..[256+u], ..[384+u] } + bias
// Thread (wave w, pl=lane>>3, q=lane&7): unit-pair p = 8w+pl, k-range [16q,16q+16).
// ---------------------------------------------------------------------------
__global__ __launch_bounds__(512, 2)
void gx_kernel(const float* __restrict__ x, const float* __restrict__ Wih2,
               const float* __restrict__ bih2, const float* __restrict__ bhh2,
               __half* __restrict__ gx)
{
  __shared__ float xs[64 * FDIM];           // 32 KB tile of x
  const int tid  = threadIdx.x;
  const int lane = tid & 63;
  const int wave = tid >> 6;
  const int q    = lane & 7;
  const int pl   = lane >> 3;
  const int p    = wave * 8 + pl;
  const int u0   = 2 * p;

  float w[8][16];
  float bias[8];
#pragma unroll
  for (int j = 0; j < 8; ++j) {
    const int row = ((j >> 1) * 128) + u0 + (j & 1);   // j = {i0,i1,f0,f1,g0,g1,o0,o1}
    const int base = row * FDIM + q * 16;
#pragma unroll
    for (int k = 0; k < 16; ++k) w[j][k] = Wih2[base + k];
    bias[j] = bih2[row] + bhh2[row];
  }

  const int t0 = blockIdx.x * 64;
  const float4* xg = (const float4*)(x + (size_t)t0 * FDIM);
  float4* xs4 = (float4*)xs;
#pragma unroll
  for (int i = 0; i < 4; ++i) xs4[tid + i * 512] = xg[tid + i * 512];
  __syncthreads();

  for (int tt = 0; tt < 64; ++tt) {
    float hv[16];
    const float4* hv4 = (const float4*)(xs + tt * FDIM + q * 16);
    *(float4*)&hv[0]  = hv4[0];
    *(float4*)&hv[4]  = hv4[1];
    *(float4*)&hv[8]  = hv4[2];
    *(float4*)&hv[12] = hv4[3];

    float acc[8];
#pragma unroll
    for (int j = 0; j < 8; ++j) {
      float a = 0.f;
#pragma unroll
      for (int k = 0; k < 16; ++k) a = fmaf(w[j][k], hv[k], a);
      acc[j] = red8(a) + bias[j];
    }
    if (q == 4) {
      // store unit-major gate quads: unit u0 -> {i0,f0,g0,o0}, u0+1 -> {i1,f1,g1,o1}
      H8 pk;
      pk.h[0] = __float2half(acc[0]); pk.h[1] = __float2half(acc[2]);
      pk.h[2] = __float2half(acc[4]); pk.h[3] = __float2half(acc[6]);
      pk.h[4] = __float2half(acc[1]); pk.h[5] = __float2half(acc[3]);
      pk.h[6] = __float2half(acc[5]); pk.h[7] = __float2half(acc[7]);
      *((uint4*)(gx + ((size_t)(t0 + tt) * FDIM + u0) * 4)) = pk.u;
    }
  }
}

// ---------------------------------------------------------------------------
// Phase B: sequential LSTM-2 scan on MFMA. One block, 512 threads, 8 waves.
// Wave w owns units 16w..16w+15.  g^T = h^T . W_hh2^T per gate via
// mfma_f32_16x16x32_f16: every lane loads the same h k-chunk (all A rows = h),
// so D[*][n] = sum_k h[k] W[gate*128+16w+n][k] in every reg; col n = lane&15.
// B fragments (W_hh2 as f16) resident in 64 VGPRs. 16 MFMA/wave/step.
// Gate math: one unit per lane (lanes 0-15). gx prefetched 8 deep.
// ---------------------------------------------------------------------------
__global__ __launch_bounds__(512, 2)
void scan_kernel(const __half* __restrict__ gx, const float* __restrict__ Whh2,
                 const float* __restrict__ h20, const float* __restrict__ c20,
                 float* __restrict__ hist)
{
  __shared__ __align__(16) __half hb[2][FDIM];
  const int tid  = threadIdx.x;
  const int lane = tid & 63;
  const int wave = tid >> 6;
  const int L    = lane & 15;     // unit-in-wave = B column
  const int jg   = lane >> 4;     // k-subgroup (0..3)
  const int unit = 16 * wave + L; // 0..127 (replicated over jg)

  // B fragments: bfr[t][kc] holds W_hh2[t*128+unit][32*kc + jg*8 + j] as f16
  f16x8 bfr[4][4];
#pragma unroll
  for (int t = 0; t < 4; ++t) {
    const float* wr = Whh2 + (size_t)(t * FDIM + unit) * FDIM;
#pragma unroll
    for (int kc = 0; kc < 4; ++kc) {
      const int k0 = 32 * kc + jg * 8;
#pragma unroll
      for (int j = 0; j < 8; ++j) bfr[t][kc][j] = (_Float16)wr[k0 + j];
    }
  }

  float c = c20[unit];            // replicated across jg groups (all valid)
  if (tid < FDIM) hb[0][tid] = __float2half(h20[tid]);

  const char* gxb = (const char*)gx;    // per-step stride: 128 units * 8 B = 1024 B
  uint2 gpf[8];
#pragma unroll
  for (int s = 0; s < 8; ++s)
    gpf[s] = *(const uint2*)(gxb + (size_t)s * 1024 + unit * 8);

  LDS_BARRIER();

  for (int t = 0; t < T_LEN; t += 8) {
#pragma unroll
    for (int s = 0; s < 8; ++s) {
      const int tt = t + s;
      const __half* hrow = hb[tt & 1];

      // A fragments: all 16 lanes of a k-subgroup read the same 16 B (broadcast)
      f16x8 af[4];
#pragma unroll
      for (int kc = 0; kc < 4; ++kc)
        af[kc] = *(const f16x8*)(hrow + 32 * kc + jg * 8);

      const uint2 gcur = gpf[s];
      gpf[s] = *(const uint2*)(gxb + (size_t)((tt + 8) & (T_LEN - 1)) * 1024 + unit * 8);

      // C-init component 0 with the gx gate value (valid in every lane)
      G4 g4; g4.u = gcur;
      f32x4 a0 = {__half2float(g4.h[0]), 0.f, 0.f, 0.f};
      f32x4 a1 = {__half2float(g4.h[1]), 0.f, 0.f, 0.f};
      f32x4 a2 = {__half2float(g4.h[2]), 0.f, 0.f, 0.f};
      f32x4 a3 = {__half2float(g4.h[3]), 0.f, 0.f, 0.f};
#pragma unroll
      for (int kc = 0; kc < 4; ++kc) {
        a0 = __builtin_amdgcn_mfma_f32_16x16x32_f16(af[kc], bfr[0][kc], a0, 0, 0, 0);
        a1 = __builtin_amdgcn_mfma_f32_16x16x32_f16(af[kc], bfr[1][kc], a1, 0, 0, 0);
        a2 = __builtin_amdgcn_mfma_f32_16x16x32_f16(af[kc], bfr[2][kc], a2, 0, 0, 0);
        a3 = __builtin_amdgcn_mfma_f32_16x16x32_f16(af[kc], bfr[3][kc], a3, 0, 0, 0);
      }

      // gate math: one unit per lane; lanes 16+ compute identical duplicates
      c = sigmoid_f(a1[0]) * c + sigmoid_f(a0[0]) * tanh_f(a2[0]);
      const float h = sigmoid_f(a3[0]) * tanh_f(c);

      if (lane < 16) {
        hb[(tt + 1) & 1][unit] = __float2half(h);
        hist[(size_t)tt * FDIM + unit] = h;      // fire-and-forget
      }
      LDS_BARRIER();
    }
  }
}

// ---------------------------------------------------------------------------
// Phase C: out[t] = 2*sigmoid(W_fc @ h2[t] + b_fc), in place on d_out.
// ---------------------------------------------------------------------------
__global__ __launch_bounds__(512, 2)
void fc_kernel(const float* __restrict__ Wfc, const float* __restrict__ bfc,
               float* __restrict__ io)
{
  __shared__ float hs[64 * FDIM];
  const int tid  = threadIdx.x;
  const int lane = tid & 63;
  const int wave = tid >> 6;
  const int q    = lane & 15;
  const int gl   = lane >> 4;
  const int g    = wave * 4 + gl;           // 0..31

  float w[4][8];
#pragma unroll
  for (int r = 0; r < 4; ++r)
#pragma unroll
    for (int k = 0; k < 8; ++k)
      w[r][k] = Wfc[(4 * g + r) * FDIM + q * 8 + k];
  const float4 bias = ((const float4*)bfc)[g];

  const int t0 = blockIdx.x * 64;
  float4* iog = (float4*)(io + (size_t)t0 * FDIM);
  float4* hs4 = (float4*)hs;
#pragma unroll
  for (int i = 0; i < 4; ++i) hs4[tid + i * 512] = iog[tid + i * 512];
  __syncthreads();          // all reads of this block's rows done before writes

  for (int tt = 0; tt < 64; ++tt) {
    float hv[8];
    const float4* hv4 = (const float4*)(hs + tt * FDIM + q * 8);
    *(float4*)&hv[0] = hv4[0];
    *(float4*)&hv[4] = hv4[1];
    float acc[4];
#pragma unroll
    for (int r = 0; r < 4; ++r) {
      float a = 0.f;
#pragma unroll
      for (int k = 0; k < 8; ++k) a = fmaf(w[r][k], hv[k], a);
      acc[r] = red16(a);
    }
    if (q == 15) {
      float4 o;
      o.x = 2.f * sigmoid_f(acc[0] + bias.x);
      o.y = 2.f * sigmoid_f(acc[1] + bias.y);
      o.z = 2.f * sigmoid_f(acc[2] + bias.z);
      o.w = 2.f * sigmoid_f(acc[3] + bias.w);
      *(float4*)(io + (size_t)(t0 + tt) * FDIM + 4 * g) = o;
    }
  }
}

// ---------------------------------------------------------------------------
extern "C" void kernel_launch(void* const* d_in, const int* in_sizes, int n_in,
                              void* d_out, int out_size, void* d_ws, size_t ws_size,
                              hipStream_t stream) {
  const float* x    = (const float*)d_in[0];
  // d_in[1..2]: h1_0/c1_0  -- layer-1 LSTM never affects the output: skipped.
  const float* h20  = (const float*)d_in[3];
  const float* c20  = (const float*)d_in[4];
  // d_in[5..8]: W_ih1/W_hh1/b_ih1/b_hh1 -- dead.
  const float* Wih2 = (const float*)d_in[9];
  const float* Whh2 = (const float*)d_in[10];
  const float* bih2 = (const float*)d_in[11];
  const float* bhh2 = (const float*)d_in[12];
  const float* Wfc  = (const float*)d_in[13];
  const float* bfc  = (const float*)d_in[14];

  float*  out = (float*)d_out;              // [T,128]: h2 history, then final out
  __half* gx  = (__half*)d_ws;              // [T][128][4] f16 gate quads (67 MB)

  gx_kernel<<<T_LEN / 64, 512, 0, stream>>>(x, Wih2, bih2, bhh2, gx);
  scan_kernel<<<1, 512, 0, stream>>>(gx, Whh2, h20, c20, out);
  fc_kernel<<<T_LEN / 64, 512, 0, stream>>>(Wfc, bfc, out);
}

// Round 4
// 20277.888 us; speedup vs baseline: 3.0507x; 1.3981x over previous
//
#include <hip/hip_runtime.h>
#include <hip/hip_fp16.h>

#define T_LEN 65536
#define FDIM  128
#define NGATE 512   // 4*F for layer-2 LSTM

typedef int iv4 __attribute__((ext_vector_type(4)));

// ---------- fast math helpers ----------
__device__ __forceinline__ float frcp(float x) { return __builtin_amdgcn_rcpf(x); }
#define LOG2E 1.4426950408889634f
__device__ __forceinline__ float sigmoid_f(float x) {
  return frcp(1.f + __builtin_amdgcn_exp2f(-LOG2E * x));
}
__device__ __forceinline__ float tanh_f(float x) {
  return 1.f - 2.f * frcp(__builtin_amdgcn_exp2f(2.f * LOG2E * x) + 1.f);
}

// ---------- DPP cross-lane reduce (Phase A/C only) ----------
template<int CTRL, int ROWM, int BANKM, bool BC>
__device__ __forceinline__ float dpp_mov0(float x) {
  return __int_as_float(
      __builtin_amdgcn_update_dpp(0, __float_as_int(x), CTRL, ROWM, BANKM, BC));
}
__device__ __forceinline__ float red8(float a) {
  a += dpp_mov0<0xB1, 0xF, 0xF, true>(a);   // quad_perm xor-1
  a += dpp_mov0<0x4E, 0xF, 0xF, true>(a);   // quad_perm xor-2
  a += dpp_mov0<0x114, 0xF, 0xA, true>(a);  // row_shr:4, banks 1&3
  return a;
}
__device__ __forceinline__ float red16(float a) {
  a += dpp_mov0<0x111, 0xF, 0xF, true>(a);
  a += dpp_mov0<0x112, 0xF, 0xF, true>(a);
  a += dpp_mov0<0x114, 0xF, 0xF, true>(a);
  a += dpp_mov0<0x118, 0xF, 0xF, true>(a);
  return a;
}

union H8 { uint4 u; __half h[8]; };
union G4 { uint2 u; __half h[4]; };

// barrier draining ONLY lgkm (LDS): no per-step vmcnt round-trip.
#define LDS_BARRIER() asm volatile("s_waitcnt lgkmcnt(0)\n\ts_barrier" ::: "memory")

// ---------------------------------------------------------------------------
// Phase A: per-unit gate precompute, stored as [T][128] x {i,f,g,o} f16 quads.
// ---------------------------------------------------------------------------
__global__ __launch_bounds__(512, 2)
void gx_kernel(const float* __restrict__ x, const float* __restrict__ Wih2,
               const float* __restrict__ bih2, const float* __restrict__ bhh2,
               __half* __restrict__ gx)
{
  __shared__ float xs[64 * FDIM];           // 32 KB tile of x
  const int tid  = threadIdx.x;
  const int lane = tid & 63;
  const int wave = tid >> 6;
  const int q    = lane & 7;
  const int pl   = lane >> 3;
  const int p    = wave * 8 + pl;
  const int u0   = 2 * p;

  float w[8][16];
  float bias[8];
#pragma unroll
  for (int j = 0; j < 8; ++j) {
    const int row = ((j >> 1) * 128) + u0 + (j & 1);   // j = {i0,i1,f0,f1,g0,g1,o0,o1}
    const int base = row * FDIM + q * 16;
#pragma unroll
    for (int k = 0; k < 16; ++k) w[j][k] = Wih2[base + k];
    bias[j] = bih2[row] + bhh2[row];
  }

  const int t0 = blockIdx.x * 64;
  const float4* xg = (const float4*)(x + (size_t)t0 * FDIM);
  float4* xs4 = (float4*)xs;
#pragma unroll
  for (int i = 0; i < 4; ++i) xs4[tid + i * 512] = xg[tid + i * 512];
  __syncthreads();

  for (int tt = 0; tt < 64; ++tt) {
    float hv[16];
    const float4* hv4 = (const float4*)(xs + tt * FDIM + q * 16);
    *(float4*)&hv[0]  = hv4[0];
    *(float4*)&hv[4]  = hv4[1];
    *(float4*)&hv[8]  = hv4[2];
    *(float4*)&hv[12] = hv4[3];

    float acc[8];
#pragma unroll
    for (int j = 0; j < 8; ++j) {
      float a = 0.f;
#pragma unroll
      for (int k = 0; k < 16; ++k) a = fmaf(w[j][k], hv[k], a);
      acc[j] = red8(a) + bias[j];
    }
    if (q == 4) {
      // store unit-major gate quads: unit u0 -> {i0,f0,g0,o0}, u0+1 -> {i1,f1,g1,o1}
      H8 pk;
      pk.h[0] = __float2half(acc[0]); pk.h[1] = __float2half(acc[2]);
      pk.h[2] = __float2half(acc[4]); pk.h[3] = __float2half(acc[6]);
      pk.h[4] = __float2half(acc[1]); pk.h[5] = __float2half(acc[3]);
      pk.h[6] = __float2half(acc[5]); pk.h[7] = __float2half(acc[7]);
      *((uint4*)(gx + ((size_t)(t0 + tt) * FDIM + u0) * 4)) = pk.u;
    }
  }
}

// ---------------------------------------------------------------------------
// Phase B: sequential LSTM-2 scan on int8 MFMA. One block, 256 threads,
// 4 waves (1 per SIMD). Wave w owns units 32w..32w+31 via two 16-col chains
// (X=0: units +0..15, X=1: units +16..31).
//   g^T = h^T . W_hh2^T per gate via mfma_i32_16x16x64_i8:
//   all lanes in a k-subgroup load the same h_q bytes (A rows identical), so
//   D[*][n] = dot_int for unit-col n in every reg; col n = lane&15.
// W_hh2 quantized once to int8 with per-row scales (exact int32 accumulate;
// dequant = 1 cvt + 1 fma). h quantized to int8 each step (|h|<1 -> scale 127).
// 16 MFMAs/wave/step (2 chained per gate-chain), ~2x faster pipe than f16.
// Gate math: one unit per lane (lanes 0-31). gx prefetched 8 deep.
// ---------------------------------------------------------------------------
__global__ __launch_bounds__(256, 1)
void scan_kernel(const __half* __restrict__ gx, const float* __restrict__ Whh2,
                 const float* __restrict__ h20, const float* __restrict__ c20,
                 float* __restrict__ hist)
{
  __shared__ __align__(16) signed char hq[2][FDIM];   // int8 h, double-buffered
  __shared__ float smax[512 * 4];                     // init-only row-max scratch

  const int tid  = threadIdx.x;
  const int lane = tid & 63;
  const int wave = tid >> 6;      // 0..3
  const int n    = lane & 15;     // MFMA column
  const int jg   = lane >> 4;     // k-subgroup 0..3
  const int X    = jg & 1;        // which chain this lane's gate-math uses
  const int ul   = lane & 31;
  const int u    = 32 * wave + ul;   // unit for gate math (lanes 32-63 duplicate)

  // ---- init pass 1: per-row |W| maxima (row = gate*128 + unit) ----
#pragma unroll
  for (int Xc = 0; Xc < 2; ++Xc) {
    const int urow = 32 * wave + 16 * Xc + n;
#pragma unroll
    for (int g = 0; g < 4; ++g) {
      const float* wr = Whh2 + (size_t)(g * FDIM + urow) * FDIM + 16 * jg;
      float m = 0.f;
#pragma unroll
      for (int kc = 0; kc < 2; ++kc)
#pragma unroll
        for (int j = 0; j < 16; ++j)
          m = fmaxf(m, fabsf(wr[64 * kc + j]));
      smax[((((wave * 2 + Xc) * 4 + g) * 16) + n) * 4 + jg] = m;
    }
  }
  __syncthreads();

  // ---- init pass 2: quantize W into resident int8 B-fragments ----
  iv4 bq[2][4][2];          // [chain X][gate][k-chunk], 16 bytes each
  float scC[2][4];          // dequant scales per chain/gate
#pragma unroll
  for (int Xc = 0; Xc < 2; ++Xc) {
    const int urow = 32 * wave + 16 * Xc + n;
#pragma unroll
    for (int g = 0; g < 4; ++g) {
      const int rowid = (((wave * 2 + Xc) * 4 + g) * 16) + n;
      float s = fmaxf(fmaxf(smax[rowid * 4 + 0], smax[rowid * 4 + 1]),
                      fmaxf(smax[rowid * 4 + 2], smax[rowid * 4 + 3]));
      s = fmaxf(s, 1e-20f);
      scC[Xc][g] = s * (1.f / 16129.f);    // s/127 * 1/127
      const float inv = 127.f / s;
      const float* wr = Whh2 + (size_t)(g * FDIM + urow) * FDIM + 16 * jg;
#pragma unroll
      for (int kc = 0; kc < 2; ++kc) {
        iv4 frag;
#pragma unroll
        for (int r = 0; r < 4; ++r) {
          int packed = 0;
#pragma unroll
          for (int b = 0; b < 4; ++b) {
            int qv = (int)rintf(wr[64 * kc + 4 * r + b] * inv);
            qv = qv < -127 ? -127 : (qv > 127 ? 127 : qv);
            packed |= (qv & 255) << (8 * b);
          }
          frag[r] = packed;
        }
        bq[Xc][g][kc] = frag;
      }
    }
  }

  // per-lane dequant scale for this lane's gate-math chain
  float scl[4];
#pragma unroll
  for (int g = 0; g < 4; ++g) scl[g] = X ? scC[1][g] : scC[0][g];

  float c = c20[u];
  if (tid < FDIM) {
    float hv = fminf(fmaxf(h20[tid], -1.f), 1.f);
    hq[0][tid] = (signed char)(int)rintf(127.f * hv);
  }

  const char* gxb = (const char*)gx;    // per-step stride: 128 units * 8 B
  uint2 gpf[8];
#pragma unroll
  for (int s = 0; s < 8; ++s)
    gpf[s] = *(const uint2*)(gxb + (size_t)s * 1024 + u * 8);

  const iv4 zero = {0, 0, 0, 0};
  __syncthreads();

  for (int t = 0; t < T_LEN; t += 8) {
#pragma unroll
    for (int s = 0; s < 8; ++s) {
      const int tt = t + s;
      const signed char* hrow = hq[tt & 1];

      // A fragments: 16 bytes per lane, broadcast within each k-subgroup
      const iv4 a0 = *(const iv4*)(hrow + jg * 16);        // k = 0..63
      const iv4 a1 = *(const iv4*)(hrow + 64 + jg * 16);   // k = 64..127

      const uint2 gcur = gpf[s];
      gpf[s] = *(const uint2*)(gxb + (size_t)((tt + 8) & (T_LEN - 1)) * 1024 + u * 8);

      iv4 acc[2][4];
#pragma unroll
      for (int Xc = 0; Xc < 2; ++Xc)
#pragma unroll
        for (int g = 0; g < 4; ++g) {
          iv4 d = __builtin_amdgcn_mfma_i32_16x16x64_i8(a0, bq[Xc][g][0], zero, 0, 0, 0);
          acc[Xc][g] = __builtin_amdgcn_mfma_i32_16x16x64_i8(a1, bq[Xc][g][1], d, 0, 0, 0);
        }

      // pick this lane's chain (values replicated across rows -> comp 0 valid)
      float dv[4];
#pragma unroll
      for (int g = 0; g < 4; ++g) {
        const int v = X ? acc[1][g][0] : acc[0][g][0];
        dv[g] = (float)v;
      }

      G4 g4; g4.u = gcur;
      const float gi = fmaf(dv[0], scl[0], __half2float(g4.h[0]));
      const float gf = fmaf(dv[1], scl[1], __half2float(g4.h[1]));
      const float gg = fmaf(dv[2], scl[2], __half2float(g4.h[2]));
      const float go = fmaf(dv[3], scl[3], __half2float(g4.h[3]));

      c = sigmoid_f(gf) * c + sigmoid_f(gi) * tanh_f(gg);
      const float h = sigmoid_f(go) * tanh_f(c);

      if (lane < 32) {
        hq[(tt + 1) & 1][u] = (signed char)(int)rintf(127.f * h);
        hist[(size_t)tt * FDIM + u] = h;     // fire-and-forget
      }
      LDS_BARRIER();
    }
  }
}

// ---------------------------------------------------------------------------
// Phase C: out[t] = 2*sigmoid(W_fc @ h2[t] + b_fc), in place on d_out.
// ---------------------------------------------------------------------------
__global__ __launch_bounds__(512, 2)
void fc_kernel(const float* __restrict__ Wfc, const float* __restrict__ bfc,
               float* __restrict__ io)
{
  __shared__ float hs[64 * FDIM];
  const int tid  = threadIdx.x;
  const int lane = tid & 63;
  const int wave = tid >> 6;
  const int q    = lane & 15;
  const int gl   = lane >> 4;
  const int g    = wave * 4 + gl;           // 0..31

  float w[4][8];
#pragma unroll
  for (int r = 0; r < 4; ++r)
#pragma unroll
    for (int k = 0; k < 8; ++k)
      w[r][k] = Wfc[(4 * g + r) * FDIM + q * 8 + k];
  const float4 bias = ((const float4*)bfc)[g];

  const int t0 = blockIdx.x * 64;
  float4* iog = (float4*)(io + (size_t)t0 * FDIM);
  float4* hs4 = (float4*)hs;
#pragma unroll
  for (int i = 0; i < 4; ++i) hs4[tid + i * 512] = iog[tid + i * 512];
  __syncthreads();          // all reads of this block's rows done before writes

  for (int tt = 0; tt < 64; ++tt) {
    float hv[8];
    const float4* hv4 = (const float4*)(hs + tt * FDIM + q * 8);
    *(float4*)&hv[0] = hv4[0];
    *(float4*)&hv[4] = hv4[1];
    float acc[4];
#pragma unroll
    for (int r = 0; r < 4; ++r) {
      float a = 0.f;
#pragma unroll
      for (int k = 0; k < 8; ++k) a = fmaf(w[r][k], hv[k], a);
      acc[r] = red16(a);
    }
    if (q == 15) {
      float4 o;
      o.x = 2.f * sigmoid_f(acc[0] + bias.x);
      o.y = 2.f * sigmoid_f(acc[1] + bias.y);
      o.z = 2.f * sigmoid_f(acc[2] + bias.z);
      o.w = 2.f * sigmoid_f(acc[3] + bias.w);
      *(float4*)(io + (size_t)(t0 + tt) * FDIM + 4 * g) = o;
    }
  }
}

// ---------------------------------------------------------------------------
extern "C" void kernel_launch(void* const* d_in, const int* in_sizes, int n_in,
                              void* d_out, int out_size, void* d_ws, size_t ws_size,
                              hipStream_t stream) {
  const float* x    = (const float*)d_in[0];
  // d_in[1..2]: h1_0/c1_0  -- layer-1 LSTM never affects the output: skipped.
  const float* h20  = (const float*)d_in[3];
  const float* c20  = (const float*)d_in[4];
  // d_in[5..8]: W_ih1/W_hh1/b_ih1/b_hh1 -- dead.
  const float* Wih2 = (const float*)d_in[9];
  const float* Whh2 = (const float*)d_in[10];
  const float* bih2 = (const float*)d_in[11];
  const float* bhh2 = (const float*)d_in[12];
  const float* Wfc  = (const float*)d_in[13];
  const float* bfc  = (const float*)d_in[14];

  float*  out = (float*)d_out;              // [T,128]: h2 history, then final out
  __half* gx  = (__half*)d_ws;              // [T][128][4] f16 gate quads (67 MB)

  gx_kernel<<<T_LEN / 64, 512, 0, stream>>>(x, Wih2, bih2, bhh2, gx);
  scan_kernel<<<1, 256, 0, stream>>>(gx, Whh2, h20, c20, out);
  fc_kernel<<<T_LEN / 64, 512, 0, stream>>>(Wfc, bfc, out);
}